// Round 6
// baseline (73.958 us; speedup 1.0000x reference)
//
#include <hip/hip_runtime.h>
#include <hip/hip_bf16.h>
#include <math.h>

#define NDIM 4096
#define MDIM 4096
#define LDIM 512
#define KDIM 1024
#define NT   16     // K-tiles of BK=64

typedef short bf16x8 __attribute__((ext_vector_type(8)));
typedef float f32x4 __attribute__((ext_vector_type(4)));

#define GLOBAL_AS __attribute__((address_space(1)))
#define LDS_AS __attribute__((address_space(3)))

__device__ __align__(16) __hip_bfloat16 g_A[(size_t)NDIM * KDIM];
__device__ __align__(16) __hip_bfloat16 g_B[(size_t)MDIM * KDIM];

__device__ __forceinline__ void gload_lds16(void* lds, const void* g) {
  __builtin_amdgcn_global_load_lds((const GLOBAL_AS void*)g, (LDS_AS void*)lds, 16, 0, 0);
}

// ---------------------------------------------------------------------------
// scale_kernel: ws[0] = |var| / sum_l exp(-0.5*lam_l)
// ---------------------------------------------------------------------------
__global__ __launch_bounds__(512) void scale_kernel(const float* __restrict__ lam,
                                                    const float* __restrict__ var,
                                                    float* __restrict__ ws) {
  int l = threadIdx.x;
  float v = expf(-0.5f * lam[l]);
  #pragma unroll
  for (int off = 32; off > 0; off >>= 1) v += __shfl_down(v, off, 64);
  __shared__ float red[8];
  if ((l & 63) == 0) red[l >> 6] = v;
  __syncthreads();
  if (l == 0) {
    float t = 0.f;
    #pragma unroll
    for (int i = 0; i < 8; ++i) t += red[i];
    ws[0] = fabsf(var[0]) / t;
  }
}

// ---------------------------------------------------------------------------
// Phase kernel: 256 threads, 2 adjacent l's/thread -> 4B packed stores.
// ---------------------------------------------------------------------------
__global__ __launch_bounds__(256) void phase_kernel(const float* __restrict__ x,
                                                    const float* __restrict__ y,
                                                    const float* __restrict__ freqs,
                                                    const float* __restrict__ lam,
                                                    const float* __restrict__ ws) {
  int t = threadIdx.x;          // 0..255
  int l0 = 2 * t, l1 = 2 * t + 1;
  int r = blockIdx.x;           // 0..8191
  float s = ws[0];
  float w0 = expf(-0.5f * lam[l0]);
  float w1 = expf(-0.5f * lam[l1]);
  float a0 = freqs[l0 * 3 + 0], a1 = freqs[l0 * 3 + 1], a2 = freqs[l0 * 3 + 2];
  float b0 = freqs[l1 * 3 + 0], b1 = freqs[l1 * 3 + 1], b2 = freqs[l1 * 3 + 2];
  bool isA = (r < NDIM);
  int rr = isA ? r : (r - NDIM);
  const float* p = isA ? (x + (size_t)rr * 3) : (y + (size_t)rr * 3);
  float p0 = p[0], p1 = p[1], p2 = p[2];
  float px0 = p0 * a0 + p1 * a1 + p2 * a2;
  float px1 = p0 * b0 + p1 * b1 + p2 * b2;
  float sn0, cs0, sn1, cs1;
  __sincosf(px0, &sn0, &cs0);
  __sincosf(px1, &sn1, &cs1);
  float g0 = isA ? (w0 * s) : 1.0f;
  float g1 = isA ? (w1 * s) : 1.0f;
  __hip_bfloat16* dst = (isA ? g_A : g_B) + (size_t)rr * KDIM;
  __hip_bfloat162 cpair, spair;
  cpair.x = __float2bfloat16(g0 * cs0); cpair.y = __float2bfloat16(g1 * cs1);
  spair.x = __float2bfloat16(g0 * sn0); spair.y = __float2bfloat16(g1 * sn1);
  *(__hip_bfloat162*)&dst[l0]        = cpair;
  *(__hip_bfloat162*)&dst[LDIM + l0] = spair;
}

// ---------------------------------------------------------------------------
// GEMM: C[4096][4096] f32 = A @ B^T, bf16, K=1024.
// 256x256 tile, BK=64, 8 waves (2Mx4N). A in LDS (64 KiB, 2-deep, swizzled,
// staged 2 phases ahead, ds-read 1 phase ahead). B direct global->reg,
// double-buffered, prefetched 1 phase ahead (L2-resident). 2 fat phases/tile,
// 32 MFMA/phase, 1 barrier/phase, counted VMCNT(4) (never 0 mid-loop).
// ---------------------------------------------------------------------------
__global__ __launch_bounds__(512, 2) void gemm_kernel(float* __restrict__ C) {
  __shared__ __align__(16) short Al[2][2][256 * 32];   // 64 KiB total

  int bid = blockIdx.x;                   // 0..255
  int swz = (bid & 7) * 32 + (bid >> 3);  // XCD swizzle (256 % 8 == 0)
  int brow = (swz >> 4) * 256;
  int bcol = (swz & 15) * 256;

  int tid  = threadIdx.x;
  int lane = tid & 63;
  int wid  = tid >> 6;                    // 0..7
  int wm   = wid >> 2;                    // 0..1 -> rows wm*128..+127
  int wn   = wid & 3;                     // 0..3 -> cols wn*64..+63

  // A ds_read offsets (swizzled: byte ^= ((row>>1)&3)<<4 within 64B rows)
  int fr   = lane & 15;
  int cs_  = ((lane >> 4) * 16) ^ (((fr >> 1) & 3) << 4);
  int offA0 = (wm * 128 + fr) * 64 + cs_;   // + m*1024 folds into imm offsets

  // A staging constants (pre-swizzled global source; LDS dest linear)
  int srow = tid >> 2;                                        // 0..127
  int scb  = ((tid & 3) * 16) ^ (((srow >> 1) & 3) << 4);     // byte in 64B row
  const short* gA = (const short*)g_A + (size_t)(brow + srow) * KDIM + scb / 2;

  // B global fragment base: col = bcol + wn*64 + n*16 + fr, k-subrow lane>>4
  const short* gBw = (const short*)g_B + (size_t)(bcol + wn * 64 + fr) * KDIM
                     + ((lane >> 4) * 8);

  f32x4 acc[8][4] = {};
  bf16x8 s0_0, s0_1, s0_2, s0_3, s0_4, s0_5, s0_6, s0_7;   // A set 0
  bf16x8 s1_0, s1_1, s1_2, s1_3, s1_4, s1_5, s1_6, s1_7;   // A set 1
  bf16x8 u0, u1, u2, u3;                                   // B set U
  bf16x8 v0, v1, v2, v3;                                   // B set V

#define STAGE(T1, KK)                                                        \
  {                                                                          \
    char* d_ = (char*)(&Al[(T1) & 1][(KK)][0]) + wid * 1024;                 \
    const short* s_ = gA + (T1) * 64 + (KK) * 32;                            \
    gload_lds16(d_, s_);                                                     \
    gload_lds16(d_ + 8192, s_ + (size_t)128 * KDIM);                         \
  }

#define VMCNT(N) asm volatile("s_waitcnt vmcnt(" #N ")" ::: "memory")
#define LGKM(N)  asm volatile("s_waitcnt lgkmcnt(" #N ")" ::: "memory")
#define SCHED0   __builtin_amdgcn_sched_barrier(0)
#define BAR      __builtin_amdgcn_s_barrier()

#define AREAD(S, T, KK)                                                      \
  { const char* Ab_ = (const char*)(&Al[(T) & 1][(KK)][0]);                  \
    S##0 = *(const bf16x8*)(Ab_ + offA0 + 0 * 1024);                         \
    S##1 = *(const bf16x8*)(Ab_ + offA0 + 1 * 1024);                         \
    S##2 = *(const bf16x8*)(Ab_ + offA0 + 2 * 1024);                         \
    S##3 = *(const bf16x8*)(Ab_ + offA0 + 3 * 1024);                         \
    S##4 = *(const bf16x8*)(Ab_ + offA0 + 4 * 1024);                         \
    S##5 = *(const bf16x8*)(Ab_ + offA0 + 5 * 1024);                         \
    S##6 = *(const bf16x8*)(Ab_ + offA0 + 6 * 1024);                         \
    S##7 = *(const bf16x8*)(Ab_ + offA0 + 7 * 1024); }

#define BGLOB(B0, B1, B2, B3, T, KK)                                         \
  { const short* p_ = gBw + (T) * 64 + (KK) * 32;                            \
    B0 = *(const bf16x8*)(p_);                                               \
    B1 = *(const bf16x8*)(p_ + 16 * KDIM);                                   \
    B2 = *(const bf16x8*)(p_ + 32 * KDIM);                                   \
    B3 = *(const bf16x8*)(p_ + 48 * KDIM); }

#define MFMA4(I, AF, B0, B1, B2, B3)                                                  \
  acc[I][0] = __builtin_amdgcn_mfma_f32_16x16x32_bf16(AF, B0, acc[I][0], 0, 0, 0);    \
  acc[I][1] = __builtin_amdgcn_mfma_f32_16x16x32_bf16(AF, B1, acc[I][1], 0, 0, 0);    \
  acc[I][2] = __builtin_amdgcn_mfma_f32_16x16x32_bf16(AF, B2, acc[I][2], 0, 0, 0);    \
  acc[I][3] = __builtin_amdgcn_mfma_f32_16x16x32_bf16(AF, B3, acc[I][3], 0, 0, 0);

#define MFMA32(S, B0, B1, B2, B3)                                            \
  __builtin_amdgcn_s_setprio(1);                                             \
  MFMA4(0, S##0, B0, B1, B2, B3) MFMA4(1, S##1, B0, B1, B2, B3)              \
  MFMA4(2, S##2, B0, B1, B2, B3) MFMA4(3, S##3, B0, B1, B2, B3)              \
  MFMA4(4, S##4, B0, B1, B2, B3) MFMA4(5, S##5, B0, B1, B2, B3)              \
  MFMA4(6, S##6, B0, B1, B2, B3) MFMA4(7, S##7, B0, B1, B2, B3)              \
  __builtin_amdgcn_s_setprio(0);

  // ---- prologue: stage A k0(0), k1(0), k0(1); load B(0,0) into U ----
  STAGE(0, 0);
  STAGE(0, 1);
  STAGE(1, 0);
  BGLOB(u0, u1, u2, u3, 0, 0);
  SCHED0;
  VMCNT(6);                      // A.k0(0), A.k1(0) landed; {A.k0(1), U} in flight
  BAR;
  AREAD(s0_, 0, 0);

  // ---- main loop t = 0..13 uniform; peel t = 14, 15 ----
  for (int t = 0; t < 14; ++t) {
    // phase (t,0): compute s0_ x U; read-ahead A.k1(t); prefetch B(t,1)->V
    AREAD(s1_, t, 1);
    BGLOB(v0, v1, v2, v3, t, 1);
    SCHED0;
    LGKM(8); SCHED0;
    MFMA32(s0_, u0, u1, u2, u3);
    STAGE(t + 1, 1);             // A.k1(t+1), read 2 phases later
    VMCNT(4);
    BAR;
    // phase (t,1): compute s1_ x V; read-ahead A.k0(t+1); prefetch B(t+1,0)->U
    AREAD(s0_, t + 1, 0);
    BGLOB(u0, u1, u2, u3, t + 1, 0);
    SCHED0;
    LGKM(8); SCHED0;
    MFMA32(s1_, v0, v1, v2, v3);
    STAGE(t + 2, 0);             // A.k0(t+2)
    VMCNT(4);
    BAR;
  }
  // t = 14
  AREAD(s1_, 14, 1);
  BGLOB(v0, v1, v2, v3, 14, 1);
  SCHED0;
  LGKM(8); SCHED0;
  MFMA32(s0_, u0, u1, u2, u3);
  STAGE(15, 1);
  VMCNT(4);
  BAR;
  AREAD(s0_, 15, 0);
  BGLOB(u0, u1, u2, u3, 15, 0);
  SCHED0;
  LGKM(8); SCHED0;
  MFMA32(s1_, v0, v1, v2, v3);
  VMCNT(4);                      // retires {V(14,1), A.k1(15)}; keeps U
  BAR;
  // t = 15
  AREAD(s1_, 15, 1);
  BGLOB(v0, v1, v2, v3, 15, 1);
  SCHED0;
  LGKM(8); SCHED0;
  MFMA32(s0_, u0, u1, u2, u3);
  LGKM(0); SCHED0;
  MFMA32(s1_, v0, v1, v2, v3);

  // ---- epilogue: C/D layout col=lane&15, row=(lane>>4)*4+j ----
  int crow = brow + wm * 128 + (lane >> 4) * 4;
  int ccol = bcol + wn * 64 + (lane & 15);
  #pragma unroll
  for (int mi = 0; mi < 8; ++mi)
    #pragma unroll
    for (int n = 0; n < 4; ++n)
      #pragma unroll
      for (int j = 0; j < 4; ++j)
        C[(size_t)(crow + mi * 16 + j) * MDIM + (ccol + n * 16)] = acc[mi][n][j];
}

extern "C" void kernel_launch(void* const* d_in, const int* in_sizes, int n_in,
                              void* d_out, int out_size, void* d_ws, size_t ws_size,
                              hipStream_t stream) {
  const float* x     = (const float*)d_in[0];
  const float* y     = (const float*)d_in[1];
  const float* freqs = (const float*)d_in[2];
  const float* lam   = (const float*)d_in[3];
  const float* var   = (const float*)d_in[4];
  float* out = (float*)d_out;
  float* ws  = (float*)d_ws;

  hipLaunchKernelGGL(scale_kernel, dim3(1), dim3(512), 0, stream, lam, var, ws);
  hipLaunchKernelGGL(phase_kernel, dim3(NDIM + MDIM), dim3(256), 0, stream,
                     x, y, freqs, lam, ws);
  hipLaunchKernelGGL(gemm_kernel, dim3((NDIM / 256) * (MDIM / 256)), dim3(512), 0, stream,
                     out);
}